// Round 6
// baseline (240.764 us; speedup 1.0000x reference)
//
#include <hip/hip_runtime.h>
#include <hip/hip_bf16.h>
#include <stdint.h>

// ---------------------------------------------------------------------------
// Cosine similarity: C[n][m] = <z_n/||z_n||, cm_m/||cm_m||>
// M=32768 rows z, Ncls=1001 rows cm, K=512, out fp32 [M][Ncls].
// Pass 1 (tiny): normalize cm rows -> bf16 bn [Npad=1024][512] in d_ws.
// Pass 2 (fused): GEMM C = bf16(z) * bn^T scaled by 1/||z_row||.
//
// R6 = R5's K-loop math (best: 83.5 us) with two targeted changes:
//   1) fp32->bf16 via v_cvt_pk_bf16_f32 (__float22bfloat162_rn) -- 1 op per
//      2 elements instead of manual f2bf's ~3-4 ops/element. Same RNE.
//   2) 256-thread blocks, 128x128 tile, grid 2048: 4 independent blocks/CU
//      (33 KB LDS, 128 total VGPR) instead of 2. Barrier groups shrink from
//      8 waves to 4, and 4 independent groups cover each other's vmcnt(0)
//      drains -- R5's diagnosis: barrier-lockstep + conversion VALU, with
//      no saturated pipe (Mfma 16/VALU 34/HBM 28%).
// Record: R0 86.6 | R1 103 | R3 100 | R4 1150 (NT-store 16x write amp) |
// R5 83.5 (swizzle: FETCH 135->43.5 MB, proves not BW-bound).
// Workspace need: 1024*512*2 B = 1 MB.
// ---------------------------------------------------------------------------

typedef short short8 __attribute__((ext_vector_type(8)));
typedef float f32x16 __attribute__((ext_vector_type(16)));

#define KDIM 512
#define BK 64

__device__ __forceinline__ unsigned short f2bf(float f) {
  uint32_t u = __float_as_uint(f);
  u += 0x7FFFu + ((u >> 16) & 1u);   // round-to-nearest-even
  return (unsigned short)(u >> 16);
}

// Pack 2 fp32 -> 2 bf16 (RNE) in one uint; emits v_cvt_pk_bf16_f32.
__device__ __forceinline__ uint32_t pk2(float a, float b) {
  union { __hip_bfloat162 h; uint32_t u; } c;
  c.h = __float22bfloat162_rn(make_float2(a, b));
  return c.u;
}

// One wave per cm row; rows >= Ncls written as zeros (GEMM B-side pad).
__global__ __launch_bounds__(256) void normalize_cm_kernel(
    const float* __restrict__ cm, unsigned short* __restrict__ bn,
    int Ncls, int Npad) {
  int r = blockIdx.x * 4 + (threadIdx.x >> 6);
  int lane = threadIdx.x & 63;
  if (r >= Npad) return;
  unsigned short* dst = bn + (size_t)r * KDIM;
  if (r >= Ncls) {
    uint2 zv = make_uint2(0u, 0u);
    *(uint2*)(dst + lane * 4) = zv;
    *(uint2*)(dst + 256 + lane * 4) = zv;
    return;
  }
  const float4* s4 = (const float4*)(cm + (size_t)r * KDIM);
  float4 x0 = s4[lane];
  float4 x1 = s4[lane + 64];
  float s = x0.x * x0.x + x0.y * x0.y + x0.z * x0.z + x0.w * x0.w +
            x1.x * x1.x + x1.y * x1.y + x1.z * x1.z + x1.w * x1.w;
#pragma unroll
  for (int off = 32; off > 0; off >>= 1) s += __shfl_xor(s, off, 64);
  float scale = 1.0f / fmaxf(sqrtf(s), 1e-8f);

  union { unsigned short u[4]; uint2 v; } p0, p1;
  p0.u[0] = f2bf(x0.x * scale); p0.u[1] = f2bf(x0.y * scale);
  p0.u[2] = f2bf(x0.z * scale); p0.u[3] = f2bf(x0.w * scale);
  p1.u[0] = f2bf(x1.x * scale); p1.u[1] = f2bf(x1.y * scale);
  p1.u[2] = f2bf(x1.z * scale); p1.u[3] = f2bf(x1.w * scale);
  *(uint2*)(dst + lane * 4) = p0.v;
  *(uint2*)(dst + 256 + lane * 4) = p1.v;
}

// Fused: C = bf16(Z) * B^T, rows scaled by 1/max(||Z_row||, 1e-8).
// Z: [M][512] fp32, B: [Npad][512] bf16 bits, C: [M][Ncls] f32.
__global__ __launch_bounds__(256, 4) void gemm_fused_kernel(
    const float* __restrict__ Z,
    const unsigned short* __restrict__ B,
    float* __restrict__ C, int M, int Ncls) {
  __shared__ unsigned short As[128 * BK];   // 16 KB (bf16)
  __shared__ unsigned short Bs[128 * BK];   // 16 KB (bf16)
  __shared__ float ns[128];                 // row ||z||^2

  const int tid = threadIdx.x;
  const int wave = tid >> 6;       // 0..3
  const int lane = tid & 63;

  // XCD-chunked bijective swizzle (nwg == 2048, % 8 == 0): within an XCD
  // the 8 N-siblings of each M-tile run consecutively -> A-panel (256 KB
  // fp32) L2-resident, reused 8x.
  const int nwg = gridDim.x;
  const int cpx = nwg >> 3;
  const int bid = blockIdx.x;
  const int wg = (bid & 7) * cpx + (bid >> 3);
  const int m0 = (wg >> 3) * 128;  // 256 M-tiles
  const int n0 = (wg & 7) * 128;   // 8 N-tiles

  const int wm = (wave & 1) * 64;  // wave's M offset
  const int wn = (wave >> 1) * 64; // wave's N offset

  // Chunk = 8 rows x 64 cols. Lane l: row l>>3, source unit (l&7)^((l>>3)&7)
  // so LDS holds unit' = u ^ (row&7) (conflict-free swizzle, as R0/R5).
  const int l3 = lane >> 3;
  const int su = (lane & 7) ^ (l3 & 7);

  // A: 4 chunks per wave (16 chunks of the 128-row tile), fp32 source.
  const float* Ag[4];
  unsigned short* Alw[4];
  // B: 4 chunks per wave (16 chunks of the 128-row tile), async bf16.
  const unsigned short* Bgp[4];
  unsigned short* Blp[4];
#pragma unroll
  for (int c = 0; c < 4; ++c) {
    int ch = wave * 4 + c;         // chunk 0..15
    Ag[c]  = Z + (size_t)(m0 + ch * 8 + l3) * KDIM + su * 8;
    Alw[c] = &As[ch * 512 + lane * 8];
    Bgp[c] = B + (size_t)(n0 + ch * 8 + l3) * KDIM + su * 8;
    Blp[c] = &Bs[ch * 512 + lane * 8];
  }

  const int fm = lane & 31;        // fragment row (A: m, B: n)
  const int kh = lane >> 5;        // k-half
  const int fx = fm & 7;           // swizzle phase

  f32x16 acc[2][2] = {};
  float rs[4] = {0.0f, 0.0f, 0.0f, 0.0f};   // per-chunk partial row ssq

  for (int k0 = 0; k0 < KDIM; k0 += BK) {
    __syncthreads();  // previous iteration's LDS reads complete
    // B: async straight to LDS (issued first; in flight during A staging).
#pragma unroll
    for (int c = 0; c < 4; ++c)
      __builtin_amdgcn_global_load_lds(
          (const __attribute__((address_space(1))) void*)(Bgp[c] + k0),
          (__attribute__((address_space(3))) void*)Blp[c], 16, 0, 0);
    // A: load fp32, accumulate ssq, cvt_pk to bf16, stage to LDS.
#pragma unroll
    for (int c = 0; c < 4; ++c) {
      float4 x0 = *(const float4*)(Ag[c] + k0);
      float4 x1 = *(const float4*)(Ag[c] + k0 + 4);
      rs[c] += x0.x * x0.x + x0.y * x0.y + x0.z * x0.z + x0.w * x0.w +
               x1.x * x1.x + x1.y * x1.y + x1.z * x1.z + x1.w * x1.w;
      uint4 v;
      v.x = pk2(x0.x, x0.y);
      v.y = pk2(x0.z, x0.w);
      v.z = pk2(x1.x, x1.y);
      v.w = pk2(x1.z, x1.w);
      *(uint4*)Alw[c] = v;
    }
    __syncthreads();  // staged tiles visible (drains B vmcnt + A lgkm)

#pragma unroll
    for (int ks = 0; ks < 4; ++ks) {
      int u = ((ks << 1) | kh) ^ fx;
      short8 a0 = *(const short8*)&As[(wm + fm) * BK + u * 8];
      short8 a1 = *(const short8*)&As[(wm + 32 + fm) * BK + u * 8];
      short8 b0 = *(const short8*)&Bs[(wn + fm) * BK + u * 8];
      short8 b1 = *(const short8*)&Bs[(wn + 32 + fm) * BK + u * 8];
      acc[0][0] = __builtin_amdgcn_mfma_f32_32x32x16_bf16(a0, b0, acc[0][0], 0, 0, 0);
      acc[0][1] = __builtin_amdgcn_mfma_f32_32x32x16_bf16(a0, b1, acc[0][1], 0, 0, 0);
      acc[1][0] = __builtin_amdgcn_mfma_f32_32x32x16_bf16(a1, b0, acc[1][0], 0, 0, 0);
      acc[1][1] = __builtin_amdgcn_mfma_f32_32x32x16_bf16(a1, b1, acc[1][1], 0, 0, 0);
    }
  }

  // Finish row norms: reduce across the 8 lanes sharing each row, publish.
#pragma unroll
  for (int c = 0; c < 4; ++c) {
#pragma unroll
    for (int off = 1; off < 8; off <<= 1) rs[c] += __shfl_xor(rs[c], off, 64);
  }
  if ((lane & 7) == 0) {
#pragma unroll
    for (int c = 0; c < 4; ++c) ns[wave * 32 + c * 8 + l3] = rs[c];
  }
  __syncthreads();

  // Epilogue: C = acc * 1/max(||z_row||, eps).
  // C/D layout (32x32): col = lane&31, row = (r&3) + 8*(r>>2) + 4*(lane>>5).
  const int cn = lane & 31;
  const int ch4 = kh * 4;
#pragma unroll
  for (int mi = 0; mi < 2; ++mi) {
    float rn[16];
#pragma unroll
    for (int q = 0; q < 4; ++q) {
      float4 n4 = *(const float4*)&ns[wm + mi * 32 + q * 8 + ch4];
      rn[q * 4 + 0] = 1.0f / fmaxf(sqrtf(n4.x), 1e-8f);
      rn[q * 4 + 1] = 1.0f / fmaxf(sqrtf(n4.y), 1e-8f);
      rn[q * 4 + 2] = 1.0f / fmaxf(sqrtf(n4.z), 1e-8f);
      rn[q * 4 + 3] = 1.0f / fmaxf(sqrtf(n4.w), 1e-8f);
    }
#pragma unroll
    for (int ni = 0; ni < 2; ++ni) {
      int n = n0 + wn + ni * 32 + cn;
      if (n < Ncls) {
        size_t base = (size_t)(m0 + wm + mi * 32 + ch4) * (size_t)Ncls + n;
#pragma unroll
        for (int r = 0; r < 16; ++r) {
          int row = (r & 3) + 8 * (r >> 2);
          C[base + (size_t)row * Ncls] = acc[mi][ni][r] * rn[r];
        }
      }
    }
  }
}

extern "C" void kernel_launch(void* const* d_in, const int* in_sizes, int n_in,
                              void* d_out, int out_size, void* d_ws, size_t ws_size,
                              hipStream_t stream) {
  const float* z  = (const float*)d_in[0];
  const float* cm = (const float*)d_in[1];
  float* out = (float*)d_out;

  const int M    = in_sizes[0] / KDIM;                 // 32768
  const int Ncls = in_sizes[1] / KDIM;                 // 1001
  const int Npad = ((Ncls + 255) / 256) * 256;         // 1024

  unsigned short* bn = (unsigned short*)d_ws;          // 1 MB

  normalize_cm_kernel<<<Npad / 4, 256, 0, stream>>>(cm, bn, Ncls, Npad);

  // 1-D grid, XCD swizzle in-kernel: (M/128) x (Npad/128) = 256 x 8 = 2048.
  const int nwg = (M / 128) * (Npad / 128);            // 2048, % 8 == 0
  gemm_fused_kernel<<<dim3(nwg), 256, 0, stream>>>(z, bn, out, M, Ncls);
}

// Round 7
// 228.877 us; speedup vs baseline: 1.0519x; 1.0519x over previous
//
#include <hip/hip_runtime.h>
#include <hip/hip_bf16.h>
#include <stdint.h>

// ---------------------------------------------------------------------------
// Cosine similarity: C[n][m] = <z_n/||z_n||, cm_m/||cm_m||>
// M=32768 rows z, Ncls=1001 rows cm, K=512, out fp32 [M][Ncls].
//
// R7: move ALL normalization/conversion out of the GEMM.
//   Pass 1: normalize_rows -- every z row AND every cm row -> unit-norm bf16
//           (zn [M][512], bn [Npad][512] in workspace, 33.8 MB).
//   Pass 2: pure bf16 GEMM C = zn * bn^T (m97-shaped):
//           tile 64x256, 256 thr (4 waves of 64x64), BK=64, both operands
//           staged via global_load_lds (10/thread/iter, zero stage VALU),
//           frags read to regs FIRST -> lgkm barrier -> issue next-tile
//           gl_lds -> MFMA over the load flight -> vmcnt barrier.
//           40 KB LDS, ~165 VGPR -> 3 blocks/CU at 4-wave granularity.
// Fallback: if ws_size < 33.8 MB, R5 path (best fused: 83.5 us) runs instead.
// Record: R0 86.6 | R1 103 | R3 100 | R4 1150 (NT stores 16x write amp) |
// R5 83.5 | R6 132 (128x128 tile: A-redundancy 2x, reverted).
// ---------------------------------------------------------------------------

typedef short short8 __attribute__((ext_vector_type(8)));
typedef float f32x16 __attribute__((ext_vector_type(16)));

#define KDIM 512
#define BK 64

__device__ __forceinline__ unsigned short f2bf(float f) {
  uint32_t u = __float_as_uint(f);
  u += 0x7FFFu + ((u >> 16) & 1u);   // round-to-nearest-even
  return (unsigned short)(u >> 16);
}

#define MFMA(a, b, c) __builtin_amdgcn_mfma_f32_32x32x16_bf16((a), (b), (c), 0, 0, 0)

// ---------------------------------------------------------------------------
// One wave per row. Rows [0,M): z -> zn. Rows [M, M+Npad): cm -> bn
// (cm rows >= Ncls zero-filled as GEMM B-side pad).
__global__ __launch_bounds__(256) void normalize_rows_kernel(
    const float* __restrict__ z, const float* __restrict__ cm,
    unsigned short* __restrict__ zn, unsigned short* __restrict__ bn,
    int M, int Ncls, int Npad) {
  int r = blockIdx.x * 4 + (threadIdx.x >> 6);
  int lane = threadIdx.x & 63;
  const float* src;
  unsigned short* dst;
  if (r < M) {
    src = z + (size_t)r * KDIM;
    dst = zn + (size_t)r * KDIM;
  } else {
    int rc = r - M;
    if (rc >= Npad) return;
    dst = bn + (size_t)rc * KDIM;
    if (rc >= Ncls) {
      uint2 zv = make_uint2(0u, 0u);
      *(uint2*)(dst + lane * 4) = zv;
      *(uint2*)(dst + 256 + lane * 4) = zv;
      return;
    }
    src = cm + (size_t)rc * KDIM;
  }
  const float4* s4 = (const float4*)src;
  float4 x0 = s4[lane];
  float4 x1 = s4[lane + 64];
  float s = x0.x * x0.x + x0.y * x0.y + x0.z * x0.z + x0.w * x0.w +
            x1.x * x1.x + x1.y * x1.y + x1.z * x1.z + x1.w * x1.w;
#pragma unroll
  for (int off = 32; off > 0; off >>= 1) s += __shfl_xor(s, off, 64);
  float scale = 1.0f / fmaxf(sqrtf(s), 1e-8f);

  union { unsigned short u[4]; uint2 v; } p0, p1;
  p0.u[0] = f2bf(x0.x * scale); p0.u[1] = f2bf(x0.y * scale);
  p0.u[2] = f2bf(x0.z * scale); p0.u[3] = f2bf(x0.w * scale);
  p1.u[0] = f2bf(x1.x * scale); p1.u[1] = f2bf(x1.y * scale);
  p1.u[2] = f2bf(x1.z * scale); p1.u[3] = f2bf(x1.w * scale);
  *(uint2*)(dst + lane * 4) = p0.v;
  *(uint2*)(dst + 256 + lane * 4) = p1.v;
}

// ---------------------------------------------------------------------------
// Pure bf16 GEMM: C = A * B^T. A: zn [M][512], B: bn [Npad][512], C f32.
// Tile 64x256, 4 waves (each 64x64: shared 64 A-rows, own 64 B-cols).
__global__ __launch_bounds__(256, 3) void gemm_bf16_kernel(
    const unsigned short* __restrict__ A,
    const unsigned short* __restrict__ B,
    float* __restrict__ C, int M, int Ncls) {
  __shared__ unsigned short As[64 * BK];    // 8 KB
  __shared__ unsigned short Bs[256 * BK];   // 32 KB

  const int tid = threadIdx.x;
  const int wave = tid >> 6;       // 0..3
  const int lane = tid & 63;

  // XCD-chunked bijective swizzle (nwg == 2048, % 8 == 0); n-tile fastest
  // within an XCD -> the 4 N-siblings sharing an A-panel run consecutively.
  const int nwg = gridDim.x;
  const int cpx = nwg >> 3;
  const int bid = blockIdx.x;
  const int wg = (bid & 7) * cpx + (bid >> 3);
  const int m0 = (wg >> 2) * 64;   // 512 M-tiles
  const int n0 = (wg & 3) * 256;   // 4 N-tiles

  const int wn = wave * 64;        // wave's N offset

  // Chunk = 8 rows x 64 cols. Lane l: row l>>3, source unit (l&7)^((l>>3)&7)
  // -> LDS[row][u'] holds source unit u'^(row&7) (proven conflict-free).
  const int l3 = lane >> 3;
  const int su = (lane & 7) ^ (l3 & 7);

  // A: 8 chunks total, 2 per wave.
  const unsigned short* Agp[2];
  unsigned short* Alp[2];
#pragma unroll
  for (int c = 0; c < 2; ++c) {
    int ch = wave * 2 + c;
    Agp[c] = A + (size_t)(m0 + ch * 8 + l3) * KDIM + su * 8;
    Alp[c] = &As[ch * 512 + lane * 8];
  }
  // B: 32 chunks total, 8 per wave.
  const unsigned short* Bgp[8];
  unsigned short* Blp[8];
#pragma unroll
  for (int c = 0; c < 8; ++c) {
    int cb = wave * 8 + c;
    Bgp[c] = B + (size_t)(n0 + cb * 8 + l3) * KDIM + su * 8;
    Blp[c] = &Bs[cb * 512 + lane * 8];
  }

  const int fm = lane & 31;        // fragment row (A: m, B: n)
  const int kh = lane >> 5;        // k-half
  const int fx = fm & 7;           // swizzle phase

  f32x16 acc[2][2] = {};

  // Prologue: stage tile 0, full drain.
#pragma unroll
  for (int c = 0; c < 2; ++c)
    __builtin_amdgcn_global_load_lds(
        (const __attribute__((address_space(1))) void*)(Agp[c]),
        (__attribute__((address_space(3))) void*)Alp[c], 16, 0, 0);
#pragma unroll
  for (int c = 0; c < 8; ++c)
    __builtin_amdgcn_global_load_lds(
        (const __attribute__((address_space(1))) void*)(Bgp[c]),
        (__attribute__((address_space(3))) void*)Blp[c], 16, 0, 0);
  __syncthreads();

  for (int t = 0; t < KDIM / BK; ++t) {
    // 1) Read ALL fragments of tile t into registers (16 x ds_read_b128).
    short8 ra0[4], ra1[4], rb0[4], rb1[4];
#pragma unroll
    for (int ks = 0; ks < 4; ++ks) {
      int u = ((ks << 1) | kh) ^ fx;
      ra0[ks] = *(const short8*)&As[fm * BK + u * 8];
      ra1[ks] = *(const short8*)&As[(32 + fm) * BK + u * 8];
      rb0[ks] = *(const short8*)&Bs[(wn + fm) * BK + u * 8];
      rb1[ks] = *(const short8*)&Bs[(wn + 32 + fm) * BK + u * 8];
    }
    // 2) Barrier: all waves' LDS reads complete (lgkm drained; vmcnt empty).
    __syncthreads();
    // 3) Issue next tile's staging -- flies under the MFMAs below.
    if (t + 1 < KDIM / BK) {
      const int k1 = (t + 1) * BK;
#pragma unroll
      for (int c = 0; c < 2; ++c)
        __builtin_amdgcn_global_load_lds(
            (const __attribute__((address_space(1))) void*)(Agp[c] + k1),
            (__attribute__((address_space(3))) void*)Alp[c], 16, 0, 0);
#pragma unroll
      for (int c = 0; c < 8; ++c)
        __builtin_amdgcn_global_load_lds(
            (const __attribute__((address_space(1))) void*)(Bgp[c] + k1),
            (__attribute__((address_space(3))) void*)Blp[c], 16, 0, 0);
    }
    // 4) MFMA from registers (covers the staging flight).
#pragma unroll
    for (int ks = 0; ks < 4; ++ks) {
      acc[0][0] = MFMA(ra0[ks], rb0[ks], acc[0][0]);
      acc[0][1] = MFMA(ra0[ks], rb1[ks], acc[0][1]);
      acc[1][0] = MFMA(ra1[ks], rb0[ks], acc[1][0]);
      acc[1][1] = MFMA(ra1[ks], rb1[ks], acc[1][1]);
    }
    // 5) Barrier with vmcnt(0): tile t+1 landed, LDS safe to read.
    if (t + 1 < KDIM / BK) __syncthreads();
  }

  // Epilogue: plain stores (operands pre-normalized -> C = acc directly).
  // C/D layout (32x32): col = lane&31, row = (r&3) + 8*(r>>2) + 4*(lane>>5).
  const int cn = lane & 31;
  const int ch4 = kh * 4;
#pragma unroll
  for (int mi = 0; mi < 2; ++mi) {
#pragma unroll
    for (int ni = 0; ni < 2; ++ni) {
      int n = n0 + wn + ni * 32 + cn;
      if (n < Ncls) {
        size_t base = (size_t)(m0 + mi * 32 + ch4) * (size_t)Ncls + n;
#pragma unroll
        for (int r = 0; r < 16; ++r) {
          int row = (r & 3) + 8 * (r >> 2);
          C[base + (size_t)row * Ncls] = acc[mi][ni][r];
        }
      }
    }
  }
}

// ===========================================================================
// Fallback path (R5, best fused: 83.5 us) -- used when ws_size < ~33.8 MB.
// ===========================================================================
__global__ __launch_bounds__(256) void normalize_cm_kernel(
    const float* __restrict__ cm, unsigned short* __restrict__ bn,
    int Ncls, int Npad) {
  int r = blockIdx.x * 4 + (threadIdx.x >> 6);
  int lane = threadIdx.x & 63;
  if (r >= Npad) return;
  unsigned short* dst = bn + (size_t)r * KDIM;
  if (r >= Ncls) {
    uint2 zv = make_uint2(0u, 0u);
    *(uint2*)(dst + lane * 4) = zv;
    *(uint2*)(dst + 256 + lane * 4) = zv;
    return;
  }
  const float4* s4 = (const float4*)(cm + (size_t)r * KDIM);
  float4 x0 = s4[lane];
  float4 x1 = s4[lane + 64];
  float s = x0.x * x0.x + x0.y * x0.y + x0.z * x0.z + x0.w * x0.w +
            x1.x * x1.x + x1.y * x1.y + x1.z * x1.z + x1.w * x1.w;
#pragma unroll
  for (int off = 32; off > 0; off >>= 1) s += __shfl_xor(s, off, 64);
  float scale = 1.0f / fmaxf(sqrtf(s), 1e-8f);
  union { unsigned short u[4]; uint2 v; } p0, p1;
  p0.u[0] = f2bf(x0.x * scale); p0.u[1] = f2bf(x0.y * scale);
  p0.u[2] = f2bf(x0.z * scale); p0.u[3] = f2bf(x0.w * scale);
  p1.u[0] = f2bf(x1.x * scale); p1.u[1] = f2bf(x1.y * scale);
  p1.u[2] = f2bf(x1.z * scale); p1.u[3] = f2bf(x1.w * scale);
  *(uint2*)(dst + lane * 4) = p0.v;
  *(uint2*)(dst + 256 + lane * 4) = p1.v;
}

__global__ __launch_bounds__(512, 4) void gemm_fused_kernel(
    const float* __restrict__ Z,
    const unsigned short* __restrict__ B,
    float* __restrict__ C, int M, int Ncls) {
  __shared__ unsigned short As[128 * BK];
  __shared__ unsigned short Bs[256 * BK];
  __shared__ float ns[128];

  const int tid = threadIdx.x;
  const int wave = tid >> 6;
  const int lane = tid & 63;
  const int nwg = gridDim.x;
  const int cpx = nwg >> 3;
  const int bid = blockIdx.x;
  const int wg = (bid & 7) * cpx + (bid >> 3);
  const int m0 = (wg >> 2) * 128;
  const int n0 = (wg & 3) * 256;
  const int wm = (wave & 1) * 64;
  const int wn = (wave >> 1) * 64;
  const int l3 = lane >> 3;
  const int su = (lane & 7) ^ (l3 & 7);
  const int chA = wave * 2;
  const float* Ag0 = Z + (size_t)(m0 + chA * 8 + l3) * KDIM + su * 8;
  const float* Ag1 = Z + (size_t)(m0 + (chA + 1) * 8 + l3) * KDIM + su * 8;
  unsigned short* Al0 = &As[chA * 512 + lane * 8];
  unsigned short* Al1 = &As[(chA + 1) * 512 + lane * 8];
  const unsigned short* Bgp[4];
  unsigned short* Blp[4];
#pragma unroll
  for (int c = 0; c < 4; ++c) {
    int cb = wave * 4 + c;
    Bgp[c] = B + (size_t)(n0 + cb * 8 + l3) * KDIM + su * 8;
    Blp[c] = &Bs[cb * 512 + lane * 8];
  }
  const int fm = lane & 31;
  const int kh = lane >> 5;
  const int fx = fm & 7;
  f32x16 acc[2][2] = {};
  float rs0 = 0.0f, rs1 = 0.0f;
  float4 p00 = *(const float4*)(Ag0);
  float4 p01 = *(const float4*)(Ag0 + 4);
  float4 p10 = *(const float4*)(Ag1);
  float4 p11 = *(const float4*)(Ag1 + 4);
  for (int k0 = 0; k0 < KDIM; k0 += BK) {
    __syncthreads();
#pragma unroll
    for (int c = 0; c < 4; ++c)
      __builtin_amdgcn_global_load_lds(
          (const __attribute__((address_space(1))) void*)(Bgp[c] + k0),
          (__attribute__((address_space(3))) void*)Blp[c], 16, 0, 0);
    rs0 += p00.x * p00.x + p00.y * p00.y + p00.z * p00.z + p00.w * p00.w +
           p01.x * p01.x + p01.y * p01.y + p01.z * p01.z + p01.w * p01.w;
    rs1 += p10.x * p10.x + p10.y * p10.y + p10.z * p10.z + p10.w * p10.w +
           p11.x * p11.x + p11.y * p11.y + p11.z * p11.z + p11.w * p11.w;
    union { unsigned short u[8]; uint4 v; } pk;
    pk.u[0] = f2bf(p00.x); pk.u[1] = f2bf(p00.y);
    pk.u[2] = f2bf(p00.z); pk.u[3] = f2bf(p00.w);
    pk.u[4] = f2bf(p01.x); pk.u[5] = f2bf(p01.y);
    pk.u[6] = f2bf(p01.z); pk.u[7] = f2bf(p01.w);
    *(uint4*)Al0 = pk.v;
    pk.u[0] = f2bf(p10.x); pk.u[1] = f2bf(p10.y);
    pk.u[2] = f2bf(p10.z); pk.u[3] = f2bf(p10.w);
    pk.u[4] = f2bf(p11.x); pk.u[5] = f2bf(p11.y);
    pk.u[6] = f2bf(p11.z); pk.u[7] = f2bf(p11.w);
    *(uint4*)Al1 = pk.v;
    __syncthreads();
    int k1 = k0 + BK;
    if (k1 < KDIM) {
      p00 = *(const float4*)(Ag0 + k1);
      p01 = *(const float4*)(Ag0 + k1 + 4);
      p10 = *(const float4*)(Ag1 + k1);
      p11 = *(const float4*)(Ag1 + k1 + 4);
    }
#pragma unroll
    for (int ks = 0; ks < 4; ++ks) {
      int u = ((ks << 1) | kh) ^ fx;
      short8 a0 = *(const short8*)&As[(wm + fm) * BK + u * 8];
      short8 a1 = *(const short8*)&As[(wm + 32 + fm) * BK + u * 8];
      short8 b0 = *(const short8*)&Bs[(wn + fm) * BK + u * 8];
      short8 b1 = *(const short8*)&Bs[(wn + 32 + fm) * BK + u * 8];
      acc[0][0] = MFMA(a0, b0, acc[0][0]);
      acc[0][1] = MFMA(a0, b1, acc[0][1]);
      acc[1][0] = MFMA(a1, b0, acc[1][0]);
      acc[1][1] = MFMA(a1, b1, acc[1][1]);
    }
  }
#pragma unroll
  for (int off = 1; off < 8; off <<= 1) {
    rs0 += __shfl_xor(rs0, off, 64);
    rs1 += __shfl_xor(rs1, off, 64);
  }
  if ((lane & 7) == 0) {
    ns[chA * 8 + l3] = rs0;
    ns[chA * 8 + 8 + l3] = rs1;
  }
  __syncthreads();
  const int cn = lane & 31;
  const int ch4 = kh * 4;
#pragma unroll
  for (int mi = 0; mi < 2; ++mi) {
    float rn[16];
#pragma unroll
    for (int q = 0; q < 4; ++q) {
      float4 n4 = *(const float4*)&ns[wm + mi * 32 + q * 8 + ch4];
      rn[q * 4 + 0] = 1.0f / fmaxf(sqrtf(n4.x), 1e-8f);
      rn[q * 4 + 1] = 1.0f / fmaxf(sqrtf(n4.y), 1e-8f);
      rn[q * 4 + 2] = 1.0f / fmaxf(sqrtf(n4.z), 1e-8f);
      rn[q * 4 + 3] = 1.0f / fmaxf(sqrtf(n4.w), 1e-8f);
    }
#pragma unroll
    for (int ni = 0; ni < 2; ++ni) {
      int n = n0 + wn + ni * 32 + cn;
      if (n < Ncls) {
        size_t base = (size_t)(m0 + wm + mi * 32 + ch4) * (size_t)Ncls + n;
#pragma unroll
        for (int r = 0; r < 16; ++r) {
          int row = (r & 3) + 8 * (r >> 2);
          C[base + (size_t)row * Ncls] = acc[mi][ni][r] * rn[r];
        }
      }
    }
  }
}

extern "C" void kernel_launch(void* const* d_in, const int* in_sizes, int n_in,
                              void* d_out, int out_size, void* d_ws, size_t ws_size,
                              hipStream_t stream) {
  const float* z  = (const float*)d_in[0];
  const float* cm = (const float*)d_in[1];
  float* out = (float*)d_out;

  const int M    = in_sizes[0] / KDIM;                 // 32768
  const int Ncls = in_sizes[1] / KDIM;                 // 1001
  const int Npad = ((Ncls + 255) / 256) * 256;         // 1024

  const size_t need = (size_t)(M + Npad) * KDIM * sizeof(unsigned short);

  if (ws_size >= need) {
    // R7 path: prepass + pure bf16 GEMM.
    unsigned short* zn = (unsigned short*)d_ws;              // 32 MB
    unsigned short* bn = zn + (size_t)M * KDIM;              // 1 MB
    normalize_rows_kernel<<<(M + Npad) / 4, 256, 0, stream>>>(
        z, cm, zn, bn, M, Ncls, Npad);
    const int nwg = (M / 64) * (Npad / 256);                 // 2048, % 8 == 0
    gemm_bf16_kernel<<<dim3(nwg), 256, 0, stream>>>(zn, bn, out, M, Ncls);
  } else {
    // Fallback: R5 fused path (workspace 1 MB).
    unsigned short* bn = (unsigned short*)d_ws;
    normalize_cm_kernel<<<Npad / 4, 256, 0, stream>>>(cm, bn, Ncls, Npad);
    const int nwg = (M / 128) * (Npad / 256);                // 1024
    gemm_fused_kernel<<<dim3(nwg), 512, 0, stream>>>(z, bn, out, M, Ncls);
  }
}